// Round 17
// baseline (701.858 us; speedup 1.0000x reference)
//
#include <hip/hip_runtime.h>
#include <hip/hip_bf16.h>
#include <math.h>

#define HWD 262144   // 64*64*64

typedef __attribute__((ext_vector_type(8))) short bf16x8;   // 8 bf16 (4 VGPRs)
typedef __attribute__((ext_vector_type(16))) float f32x16;  // MFMA 32x32 accumulator

__device__ inline unsigned short bfu(float f) {
    __hip_bfloat16 h = __float2bfloat16(f);
    return *reinterpret_cast<unsigned short*>(&h);
}

// ---------------- prep: weights -> bf16 GEMM layout A[ks 72][oc 128][kk 16]; w_map -> Wb bf16 ----
// K order: k = ((g*3+r)*3+s)*64 + z,  ks=k>>4, kk=k&15.
__global__ void k_prep(const float* __restrict__ w_t, const float* __restrict__ w_c,
                       const float* __restrict__ w_map,
                       __hip_bfloat16* __restrict__ A_t, __hip_bfloat16* __restrict__ A_c,
                       __hip_bfloat16* __restrict__ Wb) {
    int i = blockIdx.x * 256 + threadIdx.x;
    if (i < 147456) {
        int kk = i & 15, oc = (i >> 4) & 127, ks = i >> 11;
        int z4 = ks & 3, kq = ks >> 2;          // kq = (g*3+r)*3+s in [0,18)
        int g = kq / 9, tap = kq - 9 * g;       // tap = r*3+s
        int z = z4 * 16 + kk;
        // w_t (128,2,64,3,3): ((o*2+g)*64+kh)*9 + tap,  z=kh
        A_t[i] = __float2bfloat16(w_t[((oc * 2 + g) * 64 + z) * 9 + tap]);
        // w_c (128,2,3,3,64): ((o*2+g)*9+tap)*64 + kd,  z=kd
        A_c[i] = __float2bfloat16(w_c[((oc * 2 + g) * 9 + tap) * 64 + z]);
    }
    if (i < 8192) {
        Wb[i] = __float2bfloat16(w_map[i]);   // w_map is (C,2C) row-major = [c][k]
    }
}

__device__ inline void pack_row_bf16(__hip_bfloat16* dst, const float* src) {
    unsigned short u[16];
#pragma unroll
    for (int j = 0; j < 16; ++j) u[j] = bfu(src[j]);
    uint4* q = reinterpret_cast<uint4*>(dst);
    q[0] = *reinterpret_cast<const uint4*>(&u[0]);
    q[1] = *reinterpret_cast<const uint4*>(&u[8]);
}

// ---------------- merged transpose: x -> Xc (z4-plane [cg][z4][h*w][16]) and
//                  x -> Xt (z4-plane [cg][z4][w*d][16], inner 16 = h), ONE dispatch ----------
__global__ void k_trans(const float* __restrict__ x, __hip_bfloat16* __restrict__ Xc,
                        __hip_bfloat16* __restrict__ Xt) {
    __shared__ unsigned short tile[256][68];
    int b = blockIdx.y;
    int t = threadIdx.x;
    if (blockIdx.x < 1024) {
        // ---- c-variant ----
        long n0 = (long)blockIdx.x * 256;
        const float4* xp4 = (const float4*)(x + ((long)b * HWD + n0) * 64);
#pragma unroll
        for (int i = 0; i < 16; ++i) {
            int f4i = i * 256 + t;
            float4 v = xp4[f4i];
            int nl = f4i >> 4, c4 = (f4i & 15) * 4;
            ushort4 u;
            u.x = bfu(v.x); u.y = bfu(v.y); u.z = bfu(v.z); u.w = bfu(v.w);
            *(ushort4*)&tile[nl][c4] = u;
        }
        __syncthreads();
        int c = t >> 2, hwl = t & 3;
        int hw0 = blockIdx.x * 4;
        __hip_bfloat16* dst0 = Xc + (long)(b * 64 + c) * HWD + (long)(hw0 + hwl) * 16;
#pragma unroll
        for (int z4 = 0; z4 < 4; ++z4) {
            unsigned short u[16];
#pragma unroll
            for (int j = 0; j < 16; ++j) u[j] = tile[hwl * 64 + z4 * 16 + j][c];
            __hip_bfloat16* dst = dst0 + z4 * 65536;
            *(uint4*)dst = *(const uint4*)&u[0];
            *(uint4*)(dst + 8) = *(const uint4*)&u[8];
        }
    } else {
        // ---- t-variant ----
        int wd0 = (blockIdx.x - 1024) * 4;
        const float* xb = x + (long)b * HWD * 64 + (long)wd0 * 64;
#pragma unroll
        for (int i = 0; i < 16; ++i) {
            int idx = i * 256 + t;              // float4 id over 64 h x 64 f
            int h = idx >> 6, f = idx & 63;     // per h: 4 wd x 64 c = 1KB contiguous
            float4 v = *(const float4*)(xb + (long)h * 262144 + f * 4);
            int wdl = f >> 4, c4 = (f & 15) * 4;
            ushort4 u;
            u.x = bfu(v.x); u.y = bfu(v.y); u.z = bfu(v.z); u.w = bfu(v.w);
            *(ushort4*)&tile[wdl * 64 + h][c4] = u;
        }
        __syncthreads();
        int c = t >> 2, wdl = t & 3;
        __hip_bfloat16* dst0 = Xt + (long)(b * 64 + c) * HWD + (long)(wd0 + wdl) * 16;
#pragma unroll
        for (int z4 = 0; z4 < 4; ++z4) {
            unsigned short u[16];
#pragma unroll
            for (int j = 0; j < 16; ++j) u[j] = tile[wdl * 64 + z4 * 16 + j][c];
            __hip_bfloat16* dst = dst0 + z4 * 65536;
            *(uint4*)dst = *(const uint4*)&u[0];
            *(uint4*)(dst + 8) = *(const uint4*)&u[8];
        }
    }
}

// ---------------- unified MFMA conv v11: 2-deep stage prefetch -------------------------------
// R16 confirmed the in-order-vmcnt mechanism (+5%); residual = stage loads only get 512
// matrix-cycles of cover vs ~600-900cy L3 latency. v11: stage loads for kq+2 issued during
// kq (still youngest, after A-frags); the set written at kq was loaded at kq-1 and has had
// a FULL iteration to land — and the MFMA cluster's A-wait retires everything older, so
// stage_write needs NO wait. Two NAMED reg sets (P/Q), loop unrolled x2 (rule #20).
__global__ __launch_bounds__(256, 3) void k_conv_mfma(
        const __hip_bfloat16* __restrict__ Xt, const __hip_bfloat16* __restrict__ At_,
        const float* __restrict__ bt, float* __restrict__ OutT,
        const __hip_bfloat16* __restrict__ Xc, const __hip_bfloat16* __restrict__ Ac_,
        const float* __restrict__ bcb, float* __restrict__ OutC) {
    int Lfull = blockIdx.x;                   // 4096 = 2 halves x 2048
    int halfk = Lfull >> 11;
    int L = Lfull & 2047;                     // 2048 = 64 grp * 32 pt
    const __hip_bfloat16* X = halfk ? Xc : Xt;
    const __hip_bfloat16* Aglob = halfk ? Ac_ : At_;
    const float* bias = halfk ? bcb : bt;
    float* Out = halfk ? OutC : OutT;

    int grp = (L & 7) * 8 + ((L >> 3) >> 5);  // XCD r handles grps [r*8, r*8+8)
    int pt = (L >> 3) & 31;
    int b = grp >> 5, ch = grp & 31;
    int p0 = pt * 2;
    const short* Xg = (const short*)(X + ((long)(b * 64 + 2 * ch)) * HWD);
    const short* Ag = (const short*)Aglob;
    int t = threadIdx.x;
    int lane = t & 63, wv = t >> 6;
    int O0 = (wv >> 1) * 64;              // wave oc base
    int N0 = (wv & 1) * 64;               // wave n base
    int lrow = lane & 31, lq = lane >> 5;

    // LDS: [buf][z4][khalf][128 rows x 8 shorts] = 32 KB
    __shared__ __align__(16) short Bsm[2][4][2][1024];

    f32x16 acc00 = {0}, acc01 = {0}, acc10 = {0}, acc11 = {0};

    int srow = t >> 1, shalf = t & 1;
    int spr = srow >> 6, sq = srow & 63;  // (p-row, q) of the staged B-row
    const uint4 zero4 = {0u, 0u, 0u, 0u};
    uint4 p0r, p1r, p2r, p3r;             // named P set
    uint4 q0r, q1r, q2r, q3r;             // named Q set
    uint4 uA0, uA1, uA2, uA3, uA4, uA5, uA6, uA7;   // named A-frags

    auto addr_of = [&](int kq) -> const short* {
        int g = (kq >= 9) ? 1 : 0;
        int tap = kq - 9 * g;
        int r = tap / 3, s = tap - 3 * r;
        int pp = p0 + spr + r - 1, qq = sq + s - 1;
        bool ok = ((unsigned)pp < 64u) && ((unsigned)qq < 64u);
        return ok ? (Xg + (long)g * HWD + (pp * 64 + qq) * 16 + shalf * 8) : nullptr;
    };
    auto loadP = [&](int kq) {
        const short* px = addr_of(kq);
        p0r = px ? *(const uint4*)(px)           : zero4;
        p1r = px ? *(const uint4*)(px + 65536)   : zero4;
        p2r = px ? *(const uint4*)(px + 131072)  : zero4;
        p3r = px ? *(const uint4*)(px + 196608)  : zero4;
    };
    auto loadQ = [&](int kq) {
        const short* px = addr_of(kq);
        q0r = px ? *(const uint4*)(px)           : zero4;
        q1r = px ? *(const uint4*)(px + 65536)   : zero4;
        q2r = px ? *(const uint4*)(px + 131072)  : zero4;
        q3r = px ? *(const uint4*)(px + 196608)  : zero4;
    };
    auto writeP = [&](int buf) {
        *(uint4*)&Bsm[buf][0][shalf][srow * 8] = p0r;
        *(uint4*)&Bsm[buf][1][shalf][srow * 8] = p1r;
        *(uint4*)&Bsm[buf][2][shalf][srow * 8] = p2r;
        *(uint4*)&Bsm[buf][3][shalf][srow * 8] = p3r;
    };
    auto writeQ = [&](int buf) {
        *(uint4*)&Bsm[buf][0][shalf][srow * 8] = q0r;
        *(uint4*)&Bsm[buf][1][shalf][srow * 8] = q1r;
        *(uint4*)&Bsm[buf][2][shalf][srow * 8] = q2r;
        *(uint4*)&Bsm[buf][3][shalf][srow * 8] = q3r;
    };
    auto aload = [&](int kq) {
        const short* Apk = Ag + kq * 8192 + (O0 + lrow) * 16 + lq * 8;
        uA0 = *(const uint4*)(Apk);
        uA1 = *(const uint4*)(Apk + 512);
        uA2 = *(const uint4*)(Apk + 2048);
        uA3 = *(const uint4*)(Apk + 2048 + 512);
        uA4 = *(const uint4*)(Apk + 4096);
        uA5 = *(const uint4*)(Apk + 4096 + 512);
        uA6 = *(const uint4*)(Apk + 6144);
        uA7 = *(const uint4*)(Apk + 6144 + 512);
    };
    auto cluster = [&](int buf) {
        bf16x8 b0, b1;
        b0 = *(const bf16x8*)&Bsm[buf][0][lq][(N0 + lrow) * 8];
        b1 = *(const bf16x8*)&Bsm[buf][0][lq][(N0 + 32 + lrow) * 8];
        acc00 = __builtin_amdgcn_mfma_f32_32x32x16_bf16(*(bf16x8*)&uA0, b0, acc00, 0, 0, 0);
        acc01 = __builtin_amdgcn_mfma_f32_32x32x16_bf16(*(bf16x8*)&uA0, b1, acc01, 0, 0, 0);
        acc10 = __builtin_amdgcn_mfma_f32_32x32x16_bf16(*(bf16x8*)&uA1, b0, acc10, 0, 0, 0);
        acc11 = __builtin_amdgcn_mfma_f32_32x32x16_bf16(*(bf16x8*)&uA1, b1, acc11, 0, 0, 0);
        b0 = *(const bf16x8*)&Bsm[buf][1][lq][(N0 + lrow) * 8];
        b1 = *(const bf16x8*)&Bsm[buf][1][lq][(N0 + 32 + lrow) * 8];
        acc00 = __builtin_amdgcn_mfma_f32_32x32x16_bf16(*(bf16x8*)&uA2, b0, acc00, 0, 0, 0);
        acc01 = __builtin_amdgcn_mfma_f32_32x32x16_bf16(*(bf16x8*)&uA2, b1, acc01, 0, 0, 0);
        acc10 = __builtin_amdgcn_mfma_f32_32x32x16_bf16(*(bf16x8*)&uA3, b0, acc10, 0, 0, 0);
        acc11 = __builtin_amdgcn_mfma_f32_32x32x16_bf16(*(bf16x8*)&uA3, b1, acc11, 0, 0, 0);
        b0 = *(const bf16x8*)&Bsm[buf][2][lq][(N0 + lrow) * 8];
        b1 = *(const bf16x8*)&Bsm[buf][2][lq][(N0 + 32 + lrow) * 8];
        acc00 = __builtin_amdgcn_mfma_f32_32x32x16_bf16(*(bf16x8*)&uA4, b0, acc00, 0, 0, 0);
        acc01 = __builtin_amdgcn_mfma_f32_32x32x16_bf16(*(bf16x8*)&uA4, b1, acc01, 0, 0, 0);
        acc10 = __builtin_amdgcn_mfma_f32_32x32x16_bf16(*(bf16x8*)&uA5, b0, acc10, 0, 0, 0);
        acc11 = __builtin_amdgcn_mfma_f32_32x32x16_bf16(*(bf16x8*)&uA5, b1, acc11, 0, 0, 0);
        b0 = *(const bf16x8*)&Bsm[buf][3][lq][(N0 + lrow) * 8];
        b1 = *(const bf16x8*)&Bsm[buf][3][lq][(N0 + 32 + lrow) * 8];
        acc00 = __builtin_amdgcn_mfma_f32_32x32x16_bf16(*(bf16x8*)&uA6, b0, acc00, 0, 0, 0);
        acc01 = __builtin_amdgcn_mfma_f32_32x32x16_bf16(*(bf16x8*)&uA6, b1, acc01, 0, 0, 0);
        acc10 = __builtin_amdgcn_mfma_f32_32x32x16_bf16(*(bf16x8*)&uA7, b0, acc10, 0, 0, 0);
        acc11 = __builtin_amdgcn_mfma_f32_32x32x16_bf16(*(bf16x8*)&uA7, b1, acc11, 0, 0, 0);
    };

    // prologue: buf0 = kq0; P holds kq1
    loadP(0);
    writeP(0);
    __syncthreads();
    loadP(1);

    int buf = 0;
    for (int kq = 0; kq < 18; kq += 2) {
        // even iteration kq: P holds kq+1
        aload(kq);                              // A-frags first (older than Q loads)
        if (kq + 2 < 18) loadQ(kq + 2);         // youngest in queue
        cluster(buf);                           // A-wait retires P loads (issued last iter)
        writeP(buf ^ 1);                        // no extra wait needed
        __syncthreads();
        buf ^= 1;
        // odd iteration kq+1: Q holds kq+2
        aload(kq + 1);
        if (kq + 3 < 18) loadP(kq + 3);
        cluster(buf);
        if (kq + 2 < 18) {
            writeQ(buf ^ 1);
            __syncthreads();
            buf ^= 1;
        }
    }

    // store: C/D layout col=lane&31, row=(reg&3)+8*(reg>>2)+4*(lane>>5)
    long base0 = ((long)(b * 64 + 2 * ch)) * HWD + (long)p0 * 64;
    int n0l = N0 + lrow, n1l = N0 + 32 + lrow;
    long noff0 = (long)(n0l >> 6) * 64 + (n0l & 63);
    long noff1 = (long)(n1l >> 6) * 64 + (n1l & 63);
#pragma unroll
    for (int reg = 0; reg < 16; ++reg) {
        int row = (reg & 3) + 8 * (reg >> 2) + 4 * lq;
        int oc0 = O0 + row, oc1 = O0 + 32 + row;
        long cb0 = base0 + (long)(oc0 >> 6) * HWD + (long)(oc0 & 63) * 4096;
        long cb1 = base0 + (long)(oc1 >> 6) * HWD + (long)(oc1 & 63) * 4096;
        float bs0 = bias[oc0], bs1 = bias[oc1];
        Out[cb0 + noff0] = acc00[reg] + bs0;
        Out[cb0 + noff1] = acc01[reg] + bs0;
        Out[cb1 + noff0] = acc10[reg] + bs1;
        Out[cb1 + noff1] = acc11[reg] + bs1;
    }
}

// ---------------- attn v3 (MFMA): At[bc,h,w2,d] = sum_w Cc[bc,w2,h,w] * T[bc,w2,w,d] ----------
__global__ __launch_bounds__(256) void k_attn(const float* __restrict__ Cc,
        const float* __restrict__ T, __hip_bfloat16* __restrict__ At) {
    __shared__ __align__(16) __hip_bfloat16 Ms[64][72];   // [h][w] 9216B, 144B rows (16B-mult)
    __shared__ __align__(16) __hip_bfloat16 Ns[64][72];   // [d][w] 9216B, transposed T
    int L = blockIdx.x;                        // 8192 = 128 bc * 64 w2
    int xcd = L & 7, j = L >> 3;
    int bc = xcd * 16 + (j >> 6), w2 = j & 63;
    const float* Ap = Cc + ((long)bc * 64 + w2) * 4096;
    const float* Bp = T + ((long)bc * 64 + w2) * 4096;
    int t = threadIdx.x;
#pragma unroll
    for (int i = 0; i < 4; ++i) {
        int f = i * 256 + t;                   // float4 id, 1024 total
        int r = f >> 4, q4 = (f & 15) * 4;
        float4 v = *(const float4*)(Ap + r * 64 + q4);
        ushort4 u;
        u.x = bfu(v.x); u.y = bfu(v.y); u.z = bfu(v.z); u.w = bfu(v.w);
        *(ushort4*)&Ms[r][q4] = u;             // [h=r][w=q4..]
        float4 w = *(const float4*)(Bp + r * 64 + q4);
        Ns[q4 + 0][r] = __float2bfloat16(w.x); // [d][w=r] scatter (one-time transpose)
        Ns[q4 + 1][r] = __float2bfloat16(w.y);
        Ns[q4 + 2][r] = __float2bfloat16(w.z);
        Ns[q4 + 3][r] = __float2bfloat16(w.w);
    }
    __syncthreads();
    int lane = t & 63, wv = t >> 6;
    int lrow = lane & 31, lhalf = lane >> 5;
    int hq = wv >> 1, dq = wv & 1;             // output quadrant
    f32x16 acc = {0};
#pragma unroll
    for (int ks = 0; ks < 4; ++ks) {
        bf16x8 a = *(const bf16x8*)&Ms[hq * 32 + lrow][ks * 16 + lhalf * 8];
        bf16x8 bfr = *(const bf16x8*)&Ns[dq * 32 + lrow][ks * 16 + lhalf * 8];
        acc = __builtin_amdgcn_mfma_f32_32x32x16_bf16(a, bfr, acc, 0, 0, 0);
    }
    // D layout: col(d)=lane&31, row(h)=(reg&3)+8*(reg>>2)+4*lhalf
    __hip_bfloat16* Ao = At + (long)bc * HWD + w2 * 64 + dq * 32 + lrow;
#pragma unroll
    for (int reg = 0; reg < 16; ++reg) {
        int hh = hq * 32 + (reg & 3) + 8 * (reg >> 2) + 4 * lhalf;
        Ao[(long)hh * 4096] = __float2bfloat16(acc[reg]);
    }
}

// ---------------- f v4 (MFMA): F[bc,h,w,d] = sum_w2 Cc[bc,w2,h,w] * T[bc,w2,w,d] --------------
__global__ __launch_bounds__(512, 4) void k_f(const float* __restrict__ Cc,
        const float* __restrict__ T, __hip_bfloat16* __restrict__ F) {
    __shared__ __align__(16) __hip_bfloat16 As[8][64][24];  // [w][h][w2+pad] 24576B
    __shared__ __align__(16) __hip_bfloat16 Ns[8][64][24];  // [w][d][w2+pad] 24576B
    int L = blockIdx.x;               // 1024 = 128 bc * 8 wt
    int xcd = L & 7, j = L >> 3;      // j 0..127
    int bc = xcd * 16 + (j >> 3), wt = j & 7;
    const float* Ab = Cc + (long)bc * HWD;
    const float* Bb = T + (long)bc * HWD;
    int t = threadIdx.x;
    int lane = t & 63, wv = t >> 6;   // wv = local w (0..7)
    int lrow = lane & 31, lhalf = lane >> 5;
    f32x16 acc00 = {0}, acc01 = {0}, acc10 = {0}, acc11 = {0};

    for (int w2c = 0; w2c < 4; ++w2c) {
        __syncthreads();
        // A stage: Cc[kk][hh][wt*8 + half*4 ..+4], 32B-contiguous float4 pairs,
        // transposed into As[w][h][kk].
#pragma unroll
        for (int i = 0; i < 4; ++i) {
            int f = i * 512 + t;                        // 0..2047
            int half = f & 1, hh = (f >> 1) & 63, kk = f >> 7;
            float4 v = *(const float4*)(Ab + (long)(w2c * 16 + kk) * 4096 + hh * 64 + wt * 8 + half * 4);
            As[half * 4 + 0][hh][kk] = __float2bfloat16(v.x);
            As[half * 4 + 1][hh][kk] = __float2bfloat16(v.y);
            As[half * 4 + 2][hh][kk] = __float2bfloat16(v.z);
            As[half * 4 + 3][hh][kk] = __float2bfloat16(v.w);
        }
        // B stage: T[kk][wt*8+ww][d], fully coalesced float4 over d, transposed into Ns[w][d][kk].
#pragma unroll
        for (int i = 0; i < 4; ++i) {
            int f = i * 512 + t;
            int d4 = f & 15, ww = (f >> 4) & 7, kk = f >> 7;
            float4 v = *(const float4*)(Bb + (long)(w2c * 16 + kk) * 4096 + (wt * 8 + ww) * 64 + d4 * 4);
            Ns[ww][d4 * 4 + 0][kk] = __float2bfloat16(v.x);
            Ns[ww][d4 * 4 + 1][kk] = __float2bfloat16(v.y);
            Ns[ww][d4 * 4 + 2][kk] = __float2bfloat16(v.z);
            Ns[ww][d4 * 4 + 3][kk] = __float2bfloat16(v.w);
        }
        __syncthreads();
        bf16x8 a0 = *(const bf16x8*)&As[wv][lrow][lhalf * 8];
        bf16x8 a1 = *(const bf16x8*)&As[wv][32 + lrow][lhalf * 8];
        bf16x8 b0 = *(const bf16x8*)&Ns[wv][lrow][lhalf * 8];
        bf16x8 b1 = *(const bf16x8*)&Ns[wv][32 + lrow][lhalf * 8];
        acc00 = __builtin_amdgcn_mfma_f32_32x32x16_bf16(a0, b0, acc00, 0, 0, 0);
        acc01 = __builtin_amdgcn_mfma_f32_32x32x16_bf16(a0, b1, acc01, 0, 0, 0);
        acc10 = __builtin_amdgcn_mfma_f32_32x32x16_bf16(a1, b0, acc10, 0, 0, 0);
        acc11 = __builtin_amdgcn_mfma_f32_32x32x16_bf16(a1, b1, acc11, 0, 0, 0);
    }
    // store: F[bc][h][wt*8+wv][d]; D layout col(d)=lane&31, row(h)=(reg&3)+8*(reg>>2)+4*lhalf
    __hip_bfloat16* Fp = F + (long)bc * HWD + (wt * 8 + wv) * 64;
#pragma unroll
    for (int reg = 0; reg < 16; ++reg) {
        int row = (reg & 3) + 8 * (reg >> 2) + 4 * lhalf;
        Fp[(long)row * 4096 + lrow]             = __float2bfloat16(acc00[reg]);
        Fp[(long)row * 4096 + 32 + lrow]        = __float2bfloat16(acc01[reg]);
        Fp[(long)(32 + row) * 4096 + lrow]      = __float2bfloat16(acc10[reg]);
        Fp[(long)(32 + row) * 4096 + 32 + lrow] = __float2bfloat16(acc11[reg]);
    }
}

// ---------------- map v6 (MFMA): out[n][c] = gelu( sum_k P[n][k] Wb[k][c] + b_map[c] ) ----
__global__ __launch_bounds__(256, 3) void k_map(const float* __restrict__ x,
        const __hip_bfloat16* __restrict__ F, const __hip_bfloat16* __restrict__ At,
        const __hip_bfloat16* __restrict__ Wb, const float* __restrict__ b_map,
        float* __restrict__ out) {
    __shared__ float xs[2][16][257];          // 32896 B
    __shared__ __hip_bfloat16 fa[2][16][264]; // 16896 B

    int t = threadIdx.x;
    long n0 = (long)blockIdx.x * 256;
    int b = (int)(n0 >> 18);
    long nn0 = n0 & (HWD - 1);
    const float* xblk = x + n0 * 64;
    const __hip_bfloat16* Fb = F + (long)b * 64 * HWD + nn0;
    const __hip_bfloat16* Ab = At + (long)b * 64 * HWD + nn0;

    int lane = t & 63, wv = t >> 6;
    int lrow = lane & 31, lhalf = lane >> 5;

    // preload W fragments: B-operand frag for ks=kc is W[c][kc*16 + lhalf*8 ..+8]
    const short* Wp = (const short*)Wb;
    bf16x8 wb0[8], wb1[8];                    // static-indexed in unrolled loop only
#pragma unroll
    for (int kc = 0; kc < 8; ++kc) {
        uint4 u0 = *(const uint4*)(Wp + lrow * 128 + kc * 16 + lhalf * 8);
        uint4 u1 = *(const uint4*)(Wp + (32 + lrow) * 128 + kc * 16 + lhalf * 8);
        wb0[kc] = *(bf16x8*)&u0;
        wb1[kc] = *(bf16x8*)&u1;
    }

    f32x16 acc00 = {0}, acc01 = {0}, acc10 = {0}, acc11 = {0};

    // named staging registers (no arrays -> no scratch)
    float4 xa, xb_, xc_, xd;
    uint4 fe, ff;
    int nrA = t >> 2, j4A = (t & 3) * 4;
    int rowF0 = t >> 5, segF0 = t & 31;
    int rowF1 = (256 + t) >> 5, segF1 = t & 31;

    auto load_chunk = [&](int kc) {
        if (kc < 4) {
            xa  = *(const float4*)(xblk + (nrA +   0) * 64 + kc * 16 + j4A);
            xb_ = *(const float4*)(xblk + (nrA +  64) * 64 + kc * 16 + j4A);
            xc_ = *(const float4*)(xblk + (nrA + 128) * 64 + kc * 16 + j4A);
            xd  = *(const float4*)(xblk + (nrA + 192) * 64 + kc * 16 + j4A);
            fe = *(const uint4*)(Fb + (long)(kc * 16 + rowF0) * HWD + segF0 * 8);
            ff = *(const uint4*)(Fb + (long)(kc * 16 + rowF1) * HWD + segF1 * 8);
        } else {
            fe = *(const uint4*)(Ab + (long)((kc - 4) * 16 + rowF0) * HWD + segF0 * 8);
            ff = *(const uint4*)(Ab + (long)((kc - 4) * 16 + rowF1) * HWD + segF1 * 8);
        }
    };
    auto write_chunk = [&](int kc, int buf) {
        if (kc < 4) {
            xs[buf][j4A + 0][nrA +   0] = xa.x;
            xs[buf][j4A + 1][nrA +   0] = xa.y;
            xs[buf][j4A + 2][nrA +   0] = xa.z;
            xs[buf][j4A + 3][nrA +   0] = xa.w;
            xs[buf][j4A + 0][nrA +  64] = xb_.x;
            xs[buf][j4A + 1][nrA +  64] = xb_.y;
            xs[buf][j4A + 2][nrA +  64] = xb_.z;
            xs[buf][j4A + 3][nrA +  64] = xb_.w;
            xs[buf][j4A + 0][nrA + 128] = xc_.x;
            xs[buf][j4A + 1][nrA + 128] = xc_.y;
            xs[buf][j4A + 2][nrA + 128] = xc_.z;
            xs[buf][j4A + 3][nrA + 128] = xc_.w;
            xs[buf][j4A + 0][nrA + 192] = xd.x;
            xs[buf][j4A + 1][nrA + 192] = xd.y;
            xs[buf][j4A + 2][nrA + 192] = xd.z;
            xs[buf][j4A + 3][nrA + 192] = xd.w;
        }
        *(uint4*)&fa[buf][rowF0][segF0 * 8] = fe;
        *(uint4*)&fa[buf][rowF1][segF1 * 8] = ff;
    };

    load_chunk(0);
    write_chunk(0, 0);
    __syncthreads();

#pragma unroll
    for (int kc = 0; kc < 8; ++kc) {
        int buf = kc & 1;
        if (kc < 7) load_chunk(kc + 1);        // HBM latency hides under compute below
        // build P row t (16 bf16) in registers
        unsigned short pv[16];
        if (kc < 4) {
#pragma unroll
            for (int k2 = 0; k2 < 16; ++k2) {
                float p = xs[buf][k2][t] * __bfloat162float(fa[buf][k2][t]);
                pv[k2] = bfu(p);
            }
        } else {
#pragma unroll
            for (int k2 = 0; k2 < 16; ++k2)
                pv[k2] = *reinterpret_cast<const unsigned short*>(&fa[buf][k2][t]);
        }
        unsigned lo0 = (unsigned)pv[0]  | ((unsigned)pv[1]  << 16);
        unsigned lo1 = (unsigned)pv[2]  | ((unsigned)pv[3]  << 16);
        unsigned lo2 = (unsigned)pv[4]  | ((unsigned)pv[5]  << 16);
        unsigned lo3 = (unsigned)pv[6]  | ((unsigned)pv[7]  << 16);
        unsigned hi0 = (unsigned)pv[8]  | ((unsigned)pv[9]  << 16);
        unsigned hi1 = (unsigned)pv[10] | ((unsigned)pv[11] << 16);
        unsigned hi2 = (unsigned)pv[12] | ((unsigned)pv[13] << 16);
        unsigned hi3 = (unsigned)pv[14] | ((unsigned)pv[15] << 16);
        // A-frag assembly via intra-wave shuffles (no LDS, no barrier):
        int sl0 = lane & 31, sl1 = lane | 32;
        bool lowh = lane < 32;
        unsigned s00 = __shfl(hi0, sl0), s01 = __shfl(hi1, sl0);
        unsigned s02 = __shfl(hi2, sl0), s03 = __shfl(hi3, sl0);
        unsigned r00 = __shfl(lo0, sl1), r01 = __shfl(lo1, sl1);
        unsigned r02 = __shfl(lo2, sl1), r03 = __shfl(lo3, sl1);
        uint4 ua0, ua1;
        ua0.x = lowh ? lo0 : s00; ua0.y = lowh ? lo1 : s01;
        ua0.z = lowh ? lo2 : s02; ua0.w = lowh ? lo3 : s03;
        ua1.x = lowh ? r00 : hi0; ua1.y = lowh ? r01 : hi1;
        ua1.z = lowh ? r02 : hi2; ua1.w = lowh ? r03 : hi3;
        bf16x8 a0 = *(bf16x8*)&ua0;
        bf16x8 a1 = *(bf16x8*)&ua1;
        acc00 = __builtin_amdgcn_mfma_f32_32x32x16_bf16(a0, wb0[kc], acc00, 0, 0, 0);
        acc01 = __builtin_amdgcn_mfma_f32_32x32x16_bf16(a0, wb1[kc], acc01, 0, 0, 0);
        acc10 = __builtin_amdgcn_mfma_f32_32x32x16_bf16(a1, wb0[kc], acc10, 0, 0, 0);
        acc11 = __builtin_amdgcn_mfma_f32_32x32x16_bf16(a1, wb1[kc], acc11, 0, 0, 0);
        if (kc < 7) {
            write_chunk(kc + 1, buf ^ 1);      // buf^1's readers finished before last barrier
            __syncthreads();
        }
    }

    // epilogue: bias + exact GELU + store.
    // D layout: col(c) = lane&31, row(n) = (reg&3)+8*(reg>>2)+4*lhalf
    float bs0 = b_map[lrow];
    float bs1 = b_map[32 + lrow];
    const float inv_sqrt2 = 0.70710678118654752440f;
    float* ob = out + (n0 + wv * 64) * 64;
#pragma unroll
    for (int reg = 0; reg < 16; ++reg) {
        int nrow = (reg & 3) + 8 * (reg >> 2) + 4 * lhalf;
        float v00 = acc00[reg] + bs0;
        float v01 = acc01[reg] + bs1;
        float v10 = acc10[reg] + bs0;
        float v11 = acc11[reg] + bs1;
        v00 = 0.5f * v00 * (1.f + erff(v00 * inv_sqrt2));
        v01 = 0.5f * v01 * (1.f + erff(v01 * inv_sqrt2));
        v10 = 0.5f * v10 * (1.f + erff(v10 * inv_sqrt2));
        v11 = 0.5f * v11 * (1.f + erff(v11 * inv_sqrt2));
        ob[(long)nrow * 64 + lrow] = v00;            // lanes 0-31 + 32-63: 2x128B contig
        ob[(long)nrow * 64 + 32 + lrow] = v01;
        ob[(long)(32 + nrow) * 64 + lrow] = v10;
        ob[(long)(32 + nrow) * 64 + 32 + lrow] = v11;
    }
}

extern "C" void kernel_launch(void* const* d_in, const int* in_sizes, int n_in,
                              void* d_out, int out_size, void* d_ws, size_t ws_size,
                              hipStream_t stream) {
    const float* x     = (const float*)d_in[0];
    const float* w_t   = (const float*)d_in[1];
    const float* b_t   = (const float*)d_in[2];
    const float* w_c   = (const float*)d_in[3];
    const float* b_c   = (const float*)d_in[4];
    const float* w_map = (const float*)d_in[5];
    const float* b_map = (const float*)d_in[6];
    float* out = (float*)d_out;
    float* ws = (float*)d_ws;

    // ws layout (float offsets), ~269 MB total:
    //  [0,        16777216)  Xc bf16  (33.5M elem)  -> reused as At bf16 after convs
    //  [16777216, 33554432)  Xt bf16                -> reused as F bf16 after convs
    //  [33554432, 67108864)  T fp32
    //  [67108864, ...)       A_t bf16 (147456) | A_c bf16 (147456) | Wb bf16 (8192)
    __hip_bfloat16* Xc = (__hip_bfloat16*)ws;
    __hip_bfloat16* Xt = (__hip_bfloat16*)(ws + 16777216L);
    float* T = ws + 33554432L;
    float* Cc = out;                                     // d_out as scratch
    __hip_bfloat16* A_t = (__hip_bfloat16*)(ws + 67108864L);
    __hip_bfloat16* A_c = (__hip_bfloat16*)(ws + 67182592L);
    __hip_bfloat16* Wb = (__hip_bfloat16*)(ws + 67256320L);
    __hip_bfloat16* At_bf = Xc;                          // 67 MB, Xc dead after convs
    __hip_bfloat16* F_bf = Xt;                           // 67 MB, Xt dead after convs

    hipLaunchKernelGGL(k_prep, dim3(576), dim3(256), 0, stream, w_t, w_c, w_map, A_t, A_c, Wb);
    hipLaunchKernelGGL(k_trans, dim3(2048, 2), dim3(256), 0, stream, x, Xc, Xt);
    hipLaunchKernelGGL(k_conv_mfma, dim3(4096), dim3(256), 0, stream,
                       Xt, A_t, b_t, T, Xc, A_c, b_c, Cc);
    hipLaunchKernelGGL(k_attn, dim3(8192), dim3(256), 0, stream, Cc, T, At_bf);
    hipLaunchKernelGGL(k_f, dim3(1024), dim3(512), 0, stream, Cc, T, F_bf);
    hipLaunchKernelGGL(k_map, dim3(2048), dim3(256), 0, stream, x, F_bf, At_bf, Wb, b_map, out);
}

// Round 18
// 685.816 us; speedup vs baseline: 1.0234x; 1.0234x over previous
//
#include <hip/hip_runtime.h>
#include <hip/hip_bf16.h>
#include <math.h>

#define HWD 262144   // 64*64*64

typedef __attribute__((ext_vector_type(8))) short bf16x8;   // 8 bf16 (4 VGPRs)
typedef __attribute__((ext_vector_type(16))) float f32x16;  // MFMA 32x32 accumulator

__device__ inline unsigned short bfu(float f) {
    __hip_bfloat16 h = __float2bfloat16(f);
    return *reinterpret_cast<unsigned short*>(&h);
}

// ---------------- prep: weights -> bf16 GEMM layout A[ks 72][oc 128][kk 16]; w_map -> Wb bf16 ----
// K order: k = ((g*3+r)*3+s)*64 + z,  ks=k>>4, kk=k&15.
__global__ void k_prep(const float* __restrict__ w_t, const float* __restrict__ w_c,
                       const float* __restrict__ w_map,
                       __hip_bfloat16* __restrict__ A_t, __hip_bfloat16* __restrict__ A_c,
                       __hip_bfloat16* __restrict__ Wb) {
    int i = blockIdx.x * 256 + threadIdx.x;
    if (i < 147456) {
        int kk = i & 15, oc = (i >> 4) & 127, ks = i >> 11;
        int z4 = ks & 3, kq = ks >> 2;          // kq = (g*3+r)*3+s in [0,18)
        int g = kq / 9, tap = kq - 9 * g;       // tap = r*3+s
        int z = z4 * 16 + kk;
        // w_t (128,2,64,3,3): ((o*2+g)*64+kh)*9 + tap,  z=kh
        A_t[i] = __float2bfloat16(w_t[((oc * 2 + g) * 64 + z) * 9 + tap]);
        // w_c (128,2,3,3,64): ((o*2+g)*9+tap)*64 + kd,  z=kd
        A_c[i] = __float2bfloat16(w_c[((oc * 2 + g) * 9 + tap) * 64 + z]);
    }
    if (i < 8192) {
        Wb[i] = __float2bfloat16(w_map[i]);   // w_map is (C,2C) row-major = [c][k]
    }
}

__device__ inline void pack_row_bf16(__hip_bfloat16* dst, const float* src) {
    unsigned short u[16];
#pragma unroll
    for (int j = 0; j < 16; ++j) u[j] = bfu(src[j]);
    uint4* q = reinterpret_cast<uint4*>(dst);
    q[0] = *reinterpret_cast<const uint4*>(&u[0]);
    q[1] = *reinterpret_cast<const uint4*>(&u[8]);
}

// ---------------- merged transpose: x -> Xc (z4-plane [cg][z4][h*w][16]) and
//                  x -> Xt (z4-plane [cg][z4][w*d][16], inner 16 = h), ONE dispatch ----------
__global__ void k_trans(const float* __restrict__ x, __hip_bfloat16* __restrict__ Xc,
                        __hip_bfloat16* __restrict__ Xt) {
    __shared__ unsigned short tile[256][68];
    int b = blockIdx.y;
    int t = threadIdx.x;
    if (blockIdx.x < 1024) {
        // ---- c-variant ----
        long n0 = (long)blockIdx.x * 256;
        const float4* xp4 = (const float4*)(x + ((long)b * HWD + n0) * 64);
#pragma unroll
        for (int i = 0; i < 16; ++i) {
            int f4i = i * 256 + t;
            float4 v = xp4[f4i];
            int nl = f4i >> 4, c4 = (f4i & 15) * 4;
            ushort4 u;
            u.x = bfu(v.x); u.y = bfu(v.y); u.z = bfu(v.z); u.w = bfu(v.w);
            *(ushort4*)&tile[nl][c4] = u;
        }
        __syncthreads();
        int c = t >> 2, hwl = t & 3;
        int hw0 = blockIdx.x * 4;
        __hip_bfloat16* dst0 = Xc + (long)(b * 64 + c) * HWD + (long)(hw0 + hwl) * 16;
#pragma unroll
        for (int z4 = 0; z4 < 4; ++z4) {
            unsigned short u[16];
#pragma unroll
            for (int j = 0; j < 16; ++j) u[j] = tile[hwl * 64 + z4 * 16 + j][c];
            __hip_bfloat16* dst = dst0 + z4 * 65536;
            *(uint4*)dst = *(const uint4*)&u[0];
            *(uint4*)(dst + 8) = *(const uint4*)&u[8];
        }
    } else {
        // ---- t-variant ----
        int wd0 = (blockIdx.x - 1024) * 4;
        const float* xb = x + (long)b * HWD * 64 + (long)wd0 * 64;
#pragma unroll
        for (int i = 0; i < 16; ++i) {
            int idx = i * 256 + t;              // float4 id over 64 h x 64 f
            int h = idx >> 6, f = idx & 63;     // per h: 4 wd x 64 c = 1KB contiguous
            float4 v = *(const float4*)(xb + (long)h * 262144 + f * 4);
            int wdl = f >> 4, c4 = (f & 15) * 4;
            ushort4 u;
            u.x = bfu(v.x); u.y = bfu(v.y); u.z = bfu(v.z); u.w = bfu(v.w);
            *(ushort4*)&tile[wdl * 64 + h][c4] = u;
        }
        __syncthreads();
        int c = t >> 2, wdl = t & 3;
        __hip_bfloat16* dst0 = Xt + (long)(b * 64 + c) * HWD + (long)(wd0 + wdl) * 16;
#pragma unroll
        for (int z4 = 0; z4 < 4; ++z4) {
            unsigned short u[16];
#pragma unroll
            for (int j = 0; j < 16; ++j) u[j] = tile[wdl * 64 + z4 * 16 + j][c];
            __hip_bfloat16* dst = dst0 + z4 * 65536;
            *(uint4*)dst = *(const uint4*)&u[0];
            *(uint4*)(dst + 8) = *(const uint4*)&u[8];
        }
    }
}

// ---------------- unified MFMA conv v10 (R16-benched, PARKED): issue-order fix ---------------
// A-frag loads issued FIRST (oldest in vmcnt queue), stage loads for kq+1 SECOND (youngest):
// the MFMA cluster's A-wait leaves the stage loads in flight (in-order vmcnt). v11's 2-deep
// prefetch regressed (reg spill, no latency win) -> this structure is the measured floor.
__global__ __launch_bounds__(256, 3) void k_conv_mfma(
        const __hip_bfloat16* __restrict__ Xt, const __hip_bfloat16* __restrict__ At_,
        const float* __restrict__ bt, float* __restrict__ OutT,
        const __hip_bfloat16* __restrict__ Xc, const __hip_bfloat16* __restrict__ Ac_,
        const float* __restrict__ bcb, float* __restrict__ OutC) {
    int Lfull = blockIdx.x;                   // 4096 = 2 halves x 2048
    int halfk = Lfull >> 11;
    int L = Lfull & 2047;                     // 2048 = 64 grp * 32 pt
    const __hip_bfloat16* X = halfk ? Xc : Xt;
    const __hip_bfloat16* Aglob = halfk ? Ac_ : At_;
    const float* bias = halfk ? bcb : bt;
    float* Out = halfk ? OutC : OutT;

    int grp = (L & 7) * 8 + ((L >> 3) >> 5);  // XCD r handles grps [r*8, r*8+8)
    int pt = (L >> 3) & 31;
    int b = grp >> 5, ch = grp & 31;
    int p0 = pt * 2;
    const short* Xg = (const short*)(X + ((long)(b * 64 + 2 * ch)) * HWD);
    const short* Ag = (const short*)Aglob;
    int t = threadIdx.x;
    int lane = t & 63, wv = t >> 6;
    int O0 = (wv >> 1) * 64;              // wave oc base
    int N0 = (wv & 1) * 64;               // wave n base
    int lrow = lane & 31, lq = lane >> 5;

    // LDS: [buf][z4][khalf][128 rows x 8 shorts] = 32 KB
    __shared__ __align__(16) short Bsm[2][4][2][1024];

    f32x16 acc00 = {0}, acc01 = {0}, acc10 = {0}, acc11 = {0};

    int srow = t >> 1, shalf = t & 1;
    int spr = srow >> 6, sq = srow & 63;  // (p-row, q) of the staged B-row
    const uint4 zero4 = {0u, 0u, 0u, 0u};
    uint4 ld0, ld1, ld2, ld3;             // named staging regs (no arrays -> no scratch)

    auto stage_load = [&](int kq) {
        int g = (kq >= 9) ? 1 : 0;
        int tap = kq - 9 * g;
        int r = tap / 3, s = tap - 3 * r;
        int pp = p0 + spr + r - 1, qq = sq + s - 1;
        bool ok = ((unsigned)pp < 64u) && ((unsigned)qq < 64u);
        const short* px = Xg + (long)g * HWD + (pp * 64 + qq) * 16 + shalf * 8;
        ld0 = ok ? *(const uint4*)(px)           : zero4;
        ld1 = ok ? *(const uint4*)(px + 65536)   : zero4;
        ld2 = ok ? *(const uint4*)(px + 131072)  : zero4;
        ld3 = ok ? *(const uint4*)(px + 196608)  : zero4;
    };
    auto stage_write = [&](int buf) {
        *(uint4*)&Bsm[buf][0][shalf][srow * 8] = ld0;
        *(uint4*)&Bsm[buf][1][shalf][srow * 8] = ld1;
        *(uint4*)&Bsm[buf][2][shalf][srow * 8] = ld2;
        *(uint4*)&Bsm[buf][3][shalf][srow * 8] = ld3;
    };

    stage_load(0);
    stage_write(0);
    __syncthreads();

    const short* ApkB = Ag + (O0 + lrow) * 16 + lq * 8;
    int buf = 0;
    for (int kq = 0; kq < 18; ++kq) {
        // (1) A-frag loads FIRST (oldest in vmcnt queue): 8 named uint4
        const short* Apk = ApkB + kq * 8192;
        uint4 uA0 = *(const uint4*)(Apk);
        uint4 uA1 = *(const uint4*)(Apk + 512);
        uint4 uA2 = *(const uint4*)(Apk + 2048);
        uint4 uA3 = *(const uint4*)(Apk + 2048 + 512);
        uint4 uA4 = *(const uint4*)(Apk + 4096);
        uint4 uA5 = *(const uint4*)(Apk + 4096 + 512);
        uint4 uA6 = *(const uint4*)(Apk + 6144);
        uint4 uA7 = *(const uint4*)(Apk + 6144 + 512);
        // (2) stage loads for kq+1 SECOND (youngest): A-waits won't drain them
        if (kq < 17) stage_load(kq + 1);
        // (3) MFMA cluster: 512 matrix-cycles cover the stage-load latency
        bf16x8 b0, b1;
        b0 = *(const bf16x8*)&Bsm[buf][0][lq][(N0 + lrow) * 8];
        b1 = *(const bf16x8*)&Bsm[buf][0][lq][(N0 + 32 + lrow) * 8];
        acc00 = __builtin_amdgcn_mfma_f32_32x32x16_bf16(*(bf16x8*)&uA0, b0, acc00, 0, 0, 0);
        acc01 = __builtin_amdgcn_mfma_f32_32x32x16_bf16(*(bf16x8*)&uA0, b1, acc01, 0, 0, 0);
        acc10 = __builtin_amdgcn_mfma_f32_32x32x16_bf16(*(bf16x8*)&uA1, b0, acc10, 0, 0, 0);
        acc11 = __builtin_amdgcn_mfma_f32_32x32x16_bf16(*(bf16x8*)&uA1, b1, acc11, 0, 0, 0);
        b0 = *(const bf16x8*)&Bsm[buf][1][lq][(N0 + lrow) * 8];
        b1 = *(const bf16x8*)&Bsm[buf][1][lq][(N0 + 32 + lrow) * 8];
        acc00 = __builtin_amdgcn_mfma_f32_32x32x16_bf16(*(bf16x8*)&uA2, b0, acc00, 0, 0, 0);
        acc01 = __builtin_amdgcn_mfma_f32_32x32x16_bf16(*(bf16x8*)&uA2, b1, acc01, 0, 0, 0);
        acc10 = __builtin_amdgcn_mfma_f32_32x32x16_bf16(*(bf16x8*)&uA3, b0, acc10, 0, 0, 0);
        acc11 = __builtin_amdgcn_mfma_f32_32x32x16_bf16(*(bf16x8*)&uA3, b1, acc11, 0, 0, 0);
        b0 = *(const bf16x8*)&Bsm[buf][2][lq][(N0 + lrow) * 8];
        b1 = *(const bf16x8*)&Bsm[buf][2][lq][(N0 + 32 + lrow) * 8];
        acc00 = __builtin_amdgcn_mfma_f32_32x32x16_bf16(*(bf16x8*)&uA4, b0, acc00, 0, 0, 0);
        acc01 = __builtin_amdgcn_mfma_f32_32x32x16_bf16(*(bf16x8*)&uA4, b1, acc01, 0, 0, 0);
        acc10 = __builtin_amdgcn_mfma_f32_32x32x16_bf16(*(bf16x8*)&uA5, b0, acc10, 0, 0, 0);
        acc11 = __builtin_amdgcn_mfma_f32_32x32x16_bf16(*(bf16x8*)&uA5, b1, acc11, 0, 0, 0);
        b0 = *(const bf16x8*)&Bsm[buf][3][lq][(N0 + lrow) * 8];
        b1 = *(const bf16x8*)&Bsm[buf][3][lq][(N0 + 32 + lrow) * 8];
        acc00 = __builtin_amdgcn_mfma_f32_32x32x16_bf16(*(bf16x8*)&uA6, b0, acc00, 0, 0, 0);
        acc01 = __builtin_amdgcn_mfma_f32_32x32x16_bf16(*(bf16x8*)&uA6, b1, acc01, 0, 0, 0);
        acc10 = __builtin_amdgcn_mfma_f32_32x32x16_bf16(*(bf16x8*)&uA7, b0, acc10, 0, 0, 0);
        acc11 = __builtin_amdgcn_mfma_f32_32x32x16_bf16(*(bf16x8*)&uA7, b1, acc11, 0, 0, 0);
        // (4) stage write + barrier (vmcnt(0) already satisfied by the cluster)
        if (kq < 17) {
            stage_write(buf ^ 1);
            __syncthreads();
            buf ^= 1;
        }
    }

    // store: C/D layout col=lane&31, row=(reg&3)+8*(reg>>2)+4*(lane>>5)
    long base0 = ((long)(b * 64 + 2 * ch)) * HWD + (long)p0 * 64;
    int n0l = N0 + lrow, n1l = N0 + 32 + lrow;
    long noff0 = (long)(n0l >> 6) * 64 + (n0l & 63);
    long noff1 = (long)(n1l >> 6) * 64 + (n1l & 63);
#pragma unroll
    for (int reg = 0; reg < 16; ++reg) {
        int row = (reg & 3) + 8 * (reg >> 2) + 4 * lq;
        int oc0 = O0 + row, oc1 = O0 + 32 + row;
        long cb0 = base0 + (long)(oc0 >> 6) * HWD + (long)(oc0 & 63) * 4096;
        long cb1 = base0 + (long)(oc1 >> 6) * HWD + (long)(oc1 & 63) * 4096;
        float bs0 = bias[oc0], bs1 = bias[oc1];
        Out[cb0 + noff0] = acc00[reg] + bs0;
        Out[cb0 + noff1] = acc01[reg] + bs0;
        Out[cb1 + noff0] = acc10[reg] + bs1;
        Out[cb1 + noff1] = acc11[reg] + bs1;
    }
}

// ---------------- merged attn+f (both read Cc/T, disjoint outputs, no dependency) ------------
// blocks [0,4096): attn — 512 thr = 2 independent 256-thr units (sub = t>>8), XCD mapping
//   u = c8 + 8*(2q+sub) keeps both units on one XCD with ADJACENT w2 of the same bc.
// blocks [4096,5120): k_f v4 unchanged. Barrier counts uniform within each block.
// LDS union: attn 36.9KB, f 48KB -> 48KB.
__global__ __launch_bounds__(512, 4) void k_attn_f(const float* __restrict__ Cc,
        const float* __restrict__ T, __hip_bfloat16* __restrict__ At,
        __hip_bfloat16* __restrict__ F) {
    __shared__ __align__(16) char smem[49152];
    int t = threadIdx.x;
    if (blockIdx.x < 4096) {
        // ================= attn unit =================
        __hip_bfloat16 (*Ms)[64][72] = (__hip_bfloat16 (*)[64][72])smem;            // [2][64][72]
        __hip_bfloat16 (*Ns)[64][72] = (__hip_bfloat16 (*)[64][72])(smem + 18432);  // [2][64][72]
        int sub = t >> 8, tl = t & 255;
        int c8 = blockIdx.x & 7, q = blockIdx.x >> 3;      // q in [0,512)
        int j = 2 * q + sub;                               // [0,1024)
        int bc = c8 * 16 + (j >> 6), w2 = j & 63;
        const float* Ap = Cc + ((long)bc * 64 + w2) * 4096;
        const float* Bp = T + ((long)bc * 64 + w2) * 4096;
#pragma unroll
        for (int i = 0; i < 4; ++i) {
            int f = i * 256 + tl;                  // float4 id, 1024 total
            int r = f >> 4, q4 = (f & 15) * 4;
            float4 v = *(const float4*)(Ap + r * 64 + q4);
            ushort4 u;
            u.x = bfu(v.x); u.y = bfu(v.y); u.z = bfu(v.z); u.w = bfu(v.w);
            *(ushort4*)&Ms[sub][r][q4] = u;        // [h=r][w=q4..]
            float4 w = *(const float4*)(Bp + r * 64 + q4);
            Ns[sub][q4 + 0][r] = __float2bfloat16(w.x);  // [d][w=r] transpose
            Ns[sub][q4 + 1][r] = __float2bfloat16(w.y);
            Ns[sub][q4 + 2][r] = __float2bfloat16(w.z);
            Ns[sub][q4 + 3][r] = __float2bfloat16(w.w);
        }
        __syncthreads();
        int lane = tl & 63, wv = tl >> 6;
        int lrow = lane & 31, lhalf = lane >> 5;
        int hq = wv >> 1, dq = wv & 1;             // output quadrant
        f32x16 acc = {0};
#pragma unroll
        for (int ks = 0; ks < 4; ++ks) {
            bf16x8 a = *(const bf16x8*)&Ms[sub][hq * 32 + lrow][ks * 16 + lhalf * 8];
            bf16x8 bfr = *(const bf16x8*)&Ns[sub][dq * 32 + lrow][ks * 16 + lhalf * 8];
            acc = __builtin_amdgcn_mfma_f32_32x32x16_bf16(a, bfr, acc, 0, 0, 0);
        }
        // D layout: col(d)=lane&31, row(h)=(reg&3)+8*(reg>>2)+4*lhalf
        __hip_bfloat16* Ao = At + (long)bc * HWD + w2 * 64 + dq * 32 + lrow;
#pragma unroll
        for (int reg = 0; reg < 16; ++reg) {
            int hh = hq * 32 + (reg & 3) + 8 * (reg >> 2) + 4 * lhalf;
            Ao[(long)hh * 4096] = __float2bfloat16(acc[reg]);
        }
    } else {
        // ================= k_f unit (v4, unchanged logic) =================
        __hip_bfloat16 (*As)[64][24] = (__hip_bfloat16 (*)[64][24])smem;            // [8][64][24]
        __hip_bfloat16 (*Nf)[64][24] = (__hip_bfloat16 (*)[64][24])(smem + 24576);  // [8][64][24]
        int L = blockIdx.x - 4096;        // 1024 = 128 bc * 8 wt
        int xcd = L & 7, j = L >> 3;      // j 0..127
        int bc = xcd * 16 + (j >> 3), wt = j & 7;
        const float* Ab = Cc + (long)bc * HWD;
        const float* Bb = T + (long)bc * HWD;
        int lane = t & 63, wv = t >> 6;   // wv = local w (0..7)
        int lrow = lane & 31, lhalf = lane >> 5;
        f32x16 acc00 = {0}, acc01 = {0}, acc10 = {0}, acc11 = {0};

        for (int w2c = 0; w2c < 4; ++w2c) {
            __syncthreads();
            // A stage: Cc[kk][hh][wt*8 + half*4 ..+4], transposed into As[w][h][kk].
#pragma unroll
            for (int i = 0; i < 4; ++i) {
                int f = i * 512 + t;                        // 0..2047
                int half = f & 1, hh = (f >> 1) & 63, kk = f >> 7;
                float4 v = *(const float4*)(Ab + (long)(w2c * 16 + kk) * 4096 + hh * 64 + wt * 8 + half * 4);
                As[half * 4 + 0][hh][kk] = __float2bfloat16(v.x);
                As[half * 4 + 1][hh][kk] = __float2bfloat16(v.y);
                As[half * 4 + 2][hh][kk] = __float2bfloat16(v.z);
                As[half * 4 + 3][hh][kk] = __float2bfloat16(v.w);
            }
            // B stage: T[kk][wt*8+ww][d], transposed into Nf[w][d][kk].
#pragma unroll
            for (int i = 0; i < 4; ++i) {
                int f = i * 512 + t;
                int d4 = f & 15, ww = (f >> 4) & 7, kk = f >> 7;
                float4 v = *(const float4*)(Bb + (long)(w2c * 16 + kk) * 4096 + (wt * 8 + ww) * 64 + d4 * 4);
                Nf[ww][d4 * 4 + 0][kk] = __float2bfloat16(v.x);
                Nf[ww][d4 * 4 + 1][kk] = __float2bfloat16(v.y);
                Nf[ww][d4 * 4 + 2][kk] = __float2bfloat16(v.z);
                Nf[ww][d4 * 4 + 3][kk] = __float2bfloat16(v.w);
            }
            __syncthreads();
            bf16x8 a0 = *(const bf16x8*)&As[wv][lrow][lhalf * 8];
            bf16x8 a1 = *(const bf16x8*)&As[wv][32 + lrow][lhalf * 8];
            bf16x8 b0 = *(const bf16x8*)&Nf[wv][lrow][lhalf * 8];
            bf16x8 b1 = *(const bf16x8*)&Nf[wv][32 + lrow][lhalf * 8];
            acc00 = __builtin_amdgcn_mfma_f32_32x32x16_bf16(a0, b0, acc00, 0, 0, 0);
            acc01 = __builtin_amdgcn_mfma_f32_32x32x16_bf16(a0, b1, acc01, 0, 0, 0);
            acc10 = __builtin_amdgcn_mfma_f32_32x32x16_bf16(a1, b0, acc10, 0, 0, 0);
            acc11 = __builtin_amdgcn_mfma_f32_32x32x16_bf16(a1, b1, acc11, 0, 0, 0);
        }
        // store: F[bc][h][wt*8+wv][d]
        __hip_bfloat16* Fp = F + (long)bc * HWD + (wt * 8 + wv) * 64;
#pragma unroll
        for (int reg = 0; reg < 16; ++reg) {
            int row = (reg & 3) + 8 * (reg >> 2) + 4 * lhalf;
            Fp[(long)row * 4096 + lrow]             = __float2bfloat16(acc00[reg]);
            Fp[(long)row * 4096 + 32 + lrow]        = __float2bfloat16(acc01[reg]);
            Fp[(long)(32 + row) * 4096 + lrow]      = __float2bfloat16(acc10[reg]);
            Fp[(long)(32 + row) * 4096 + 32 + lrow] = __float2bfloat16(acc11[reg]);
        }
    }
}

// ---------------- map v6 (MFMA): out[n][c] = gelu( sum_k P[n][k] Wb[k][c] + b_map[c] ) ----
__global__ __launch_bounds__(256, 3) void k_map(const float* __restrict__ x,
        const __hip_bfloat16* __restrict__ F, const __hip_bfloat16* __restrict__ At,
        const __hip_bfloat16* __restrict__ Wb, const float* __restrict__ b_map,
        float* __restrict__ out) {
    __shared__ float xs[2][16][257];          // 32896 B
    __shared__ __hip_bfloat16 fa[2][16][264]; // 16896 B

    int t = threadIdx.x;
    long n0 = (long)blockIdx.x * 256;
    int b = (int)(n0 >> 18);
    long nn0 = n0 & (HWD - 1);
    const float* xblk = x + n0 * 64;
    const __hip_bfloat16* Fb = F + (long)b * 64 * HWD + nn0;
    const __hip_bfloat16* Ab = At + (long)b * 64 * HWD + nn0;

    int lane = t & 63, wv = t >> 6;
    int lrow = lane & 31, lhalf = lane >> 5;

    // preload W fragments: B-operand frag for ks=kc is W[c][kc*16 + lhalf*8 ..+8]
    const short* Wp = (const short*)Wb;
    bf16x8 wb0[8], wb1[8];                    // static-indexed in unrolled loop only
#pragma unroll
    for (int kc = 0; kc < 8; ++kc) {
        uint4 u0 = *(const uint4*)(Wp + lrow * 128 + kc * 16 + lhalf * 8);
        uint4 u1 = *(const uint4*)(Wp + (32 + lrow) * 128 + kc * 16 + lhalf * 8);
        wb0[kc] = *(bf16x8*)&u0;
        wb1[kc] = *(bf16x8*)&u1;
    }

    f32x16 acc00 = {0}, acc01 = {0}, acc10 = {0}, acc11 = {0};

    // named staging registers (no arrays -> no scratch)
    float4 xa, xb_, xc_, xd;
    uint4 fe, ff;
    int nrA = t >> 2, j4A = (t & 3) * 4;
    int rowF0 = t >> 5, segF0 = t & 31;
    int rowF1 = (256 + t) >> 5, segF1 = t & 31;

    auto load_chunk = [&](int kc) {
        if (kc < 4) {
            xa  = *(const float4*)(xblk + (nrA +   0) * 64 + kc * 16 + j4A);
            xb_ = *(const float4*)(xblk + (nrA +  64) * 64 + kc * 16 + j4A);
            xc_ = *(const float4*)(xblk + (nrA + 128) * 64 + kc * 16 + j4A);
            xd  = *(const float4*)(xblk + (nrA + 192) * 64 + kc * 16 + j4A);
            fe = *(const uint4*)(Fb + (long)(kc * 16 + rowF0) * HWD + segF0 * 8);
            ff = *(const uint4*)(Fb + (long)(kc * 16 + rowF1) * HWD + segF1 * 8);
        } else {
            fe = *(const uint4*)(Ab + (long)((kc - 4) * 16 + rowF0) * HWD + segF0 * 8);
            ff = *(const uint4*)(Ab + (long)((kc - 4) * 16 + rowF1) * HWD + segF1 * 8);
        }
    };
    auto write_chunk = [&](int kc, int buf) {
        if (kc < 4) {
            xs[buf][j4A + 0][nrA +   0] = xa.x;
            xs[buf][j4A + 1][nrA +   0] = xa.y;
            xs[buf][j4A + 2][nrA +   0] = xa.z;
            xs[buf][j4A + 3][nrA +   0] = xa.w;
            xs[buf][j4A + 0][nrA +  64] = xb_.x;
            xs[buf][j4A + 1][nrA +  64] = xb_.y;
            xs[buf][j4A + 2][nrA +  64] = xb_.z;
            xs[buf][j4A + 3][nrA +  64] = xb_.w;
            xs[buf][j4A + 0][nrA + 128] = xc_.x;
            xs[buf][j4A + 1][nrA + 128] = xc_.y;
            xs[buf][j4A + 2][nrA + 128] = xc_.z;
            xs[buf][j4A + 3][nrA + 128] = xc_.w;
            xs[buf][j4A + 0][nrA + 192] = xd.x;
            xs[buf][j4A + 1][nrA + 192] = xd.y;
            xs[buf][j4A + 2][nrA + 192] = xd.z;
            xs[buf][j4A + 3][nrA + 192] = xd.w;
        }
        *(uint4*)&fa[buf][rowF0][segF0 * 8] = fe;
        *(uint4*)&fa[buf][rowF1][segF1 * 8] = ff;
    };

    load_chunk(0);
    write_chunk(0, 0);
    __syncthreads();

#pragma unroll
    for (int kc = 0; kc < 8; ++kc) {
        int buf = kc & 1;
        if (kc < 7) load_chunk(kc + 1);        // HBM latency hides under compute below
        // build P row t (16 bf16) in registers
        unsigned short pv[16];
        if (kc < 4) {
#pragma unroll
            for (int k2 = 0; k2 < 16; ++k2) {
                float p = xs[buf][k2][t] * __bfloat162float(fa[buf][k2][t]);
                pv[k2] = bfu(p);
            }
        } else {
#pragma unroll
            for (int k2 = 0; k2 < 16; ++k2)
                pv[k2] = *reinterpret_cast<const unsigned short*>(&fa[buf][k2][t]);
        }
        unsigned lo0 = (unsigned)pv[0]  | ((unsigned)pv[1]  << 16);
        unsigned lo1 = (unsigned)pv[2]  | ((unsigned)pv[3]  << 16);
        unsigned lo2 = (unsigned)pv[4]  | ((unsigned)pv[5]  << 16);
        unsigned lo3 = (unsigned)pv[6]  | ((unsigned)pv[7]  << 16);
        unsigned hi0 = (unsigned)pv[8]  | ((unsigned)pv[9]  << 16);
        unsigned hi1 = (unsigned)pv[10] | ((unsigned)pv[11] << 16);
        unsigned hi2 = (unsigned)pv[12] | ((unsigned)pv[13] << 16);
        unsigned hi3 = (unsigned)pv[14] | ((unsigned)pv[15] << 16);
        // A-frag assembly via intra-wave shuffles (no LDS, no barrier):
        int sl0 = lane & 31, sl1 = lane | 32;
        bool lowh = lane < 32;
        unsigned s00 = __shfl(hi0, sl0), s01 = __shfl(hi1, sl0);
        unsigned s02 = __shfl(hi2, sl0), s03 = __shfl(hi3, sl0);
        unsigned r00 = __shfl(lo0, sl1), r01 = __shfl(lo1, sl1);
        unsigned r02 = __shfl(lo2, sl1), r03 = __shfl(lo3, sl1);
        uint4 ua0, ua1;
        ua0.x = lowh ? lo0 : s00; ua0.y = lowh ? lo1 : s01;
        ua0.z = lowh ? lo2 : s02; ua0.w = lowh ? lo3 : s03;
        ua1.x = lowh ? r00 : hi0; ua1.y = lowh ? r01 : hi1;
        ua1.z = lowh ? r02 : hi2; ua1.w = lowh ? r03 : hi3;
        bf16x8 a0 = *(bf16x8*)&ua0;
        bf16x8 a1 = *(bf16x8*)&ua1;
        acc00 = __builtin_amdgcn_mfma_f32_32x32x16_bf16(a0, wb0[kc], acc00, 0, 0, 0);
        acc01 = __builtin_amdgcn_mfma_f32_32x32x16_bf16(a0, wb1[kc], acc01, 0, 0, 0);
        acc10 = __builtin_amdgcn_mfma_f32_32x32x16_bf16(a1, wb0[kc], acc10, 0, 0, 0);
        acc11 = __builtin_amdgcn_mfma_f32_32x32x16_bf16(a1, wb1[kc], acc11, 0, 0, 0);
        if (kc < 7) {
            write_chunk(kc + 1, buf ^ 1);      // buf^1's readers finished before last barrier
            __syncthreads();
        }
    }

    // epilogue: bias + exact GELU + store.
    // D layout: col(c) = lane&31, row(n) = (reg&3)+8*(reg>>2)+4*lhalf
    float bs0 = b_map[lrow];
    float bs1 = b_map[32 + lrow];
    const float inv_sqrt2 = 0.70710678118654752440f;
    float* ob = out + (n0 + wv * 64) * 64;
#pragma unroll
    for (int reg = 0; reg < 16; ++reg) {
        int nrow = (reg & 3) + 8 * (reg >> 2) + 4 * lhalf;
        float v00 = acc00[reg] + bs0;
        float v01 = acc01[reg] + bs1;
        float v10 = acc10[reg] + bs0;
        float v11 = acc11[reg] + bs1;
        v00 = 0.5f * v00 * (1.f + erff(v00 * inv_sqrt2));
        v01 = 0.5f * v01 * (1.f + erff(v01 * inv_sqrt2));
        v10 = 0.5f * v10 * (1.f + erff(v10 * inv_sqrt2));
        v11 = 0.5f * v11 * (1.f + erff(v11 * inv_sqrt2));
        ob[(long)nrow * 64 + lrow] = v00;            // lanes 0-31 + 32-63: 2x128B contig
        ob[(long)nrow * 64 + 32 + lrow] = v01;
        ob[(long)(32 + nrow) * 64 + lrow] = v10;
        ob[(long)(32 + nrow) * 64 + 32 + lrow] = v11;
    }
}

extern "C" void kernel_launch(void* const* d_in, const int* in_sizes, int n_in,
                              void* d_out, int out_size, void* d_ws, size_t ws_size,
                              hipStream_t stream) {
    const float* x     = (const float*)d_in[0];
    const float* w_t   = (const float*)d_in[1];
    const float* b_t   = (const float*)d_in[2];
    const float* w_c   = (const float*)d_in[3];
    const float* b_c   = (const float*)d_in[4];
    const float* w_map = (const float*)d_in[5];
    const float* b_map = (const float*)d_in[6];
    float* out = (float*)d_out;
    float* ws = (float*)d_ws;

    // ws layout (float offsets), ~269 MB total:
    //  [0,        16777216)  Xc bf16  (33.5M elem)  -> reused as At bf16 after convs
    //  [16777216, 33554432)  Xt bf16                -> reused as F bf16 after convs
    //  [33554432, 67108864)  T fp32
    //  [67108864, ...)       A_t bf16 (147456) | A_c bf16 (147456) | Wb bf16 (8192)
    __hip_bfloat16* Xc = (__hip_bfloat16*)ws;
    __hip_bfloat16* Xt = (__hip_bfloat16*)(ws + 16777216L);
    float* T = ws + 33554432L;
    float* Cc = out;                                     // d_out as scratch
    __hip_bfloat16* A_t = (__hip_bfloat16*)(ws + 67108864L);
    __hip_bfloat16* A_c = (__hip_bfloat16*)(ws + 67182592L);
    __hip_bfloat16* Wb = (__hip_bfloat16*)(ws + 67256320L);
    __hip_bfloat16* At_bf = Xc;                          // 67 MB, Xc dead after convs
    __hip_bfloat16* F_bf = Xt;                           // 67 MB, Xt dead after convs

    hipLaunchKernelGGL(k_prep, dim3(576), dim3(256), 0, stream, w_t, w_c, w_map, A_t, A_c, Wb);
    hipLaunchKernelGGL(k_trans, dim3(2048, 2), dim3(256), 0, stream, x, Xc, Xt);
    hipLaunchKernelGGL(k_conv_mfma, dim3(4096), dim3(256), 0, stream,
                       Xt, A_t, b_t, T, Xc, A_c, b_c, Cc);
    hipLaunchKernelGGL(k_attn_f, dim3(5120), dim3(512), 0, stream, Cc, T, At_bf, F_bf);
    hipLaunchKernelGGL(k_map, dim3(2048), dim3(256), 0, stream, x, F_bf, At_bf, Wb, b_map, out);
}